// Round 7
// baseline (476.799 us; speedup 1.0000x reference)
//
#include <hip/hip_runtime.h>
#include <hip/hip_bf16.h>

#define NNODES 50000
#define NEDGES 800000
#define DF 128
#define KW 1152                // K per branch: 128 silu + 1024 spline (native order)
#define EPS 0.001f
#define XSS 132                // Xs row stride in bf16 elems (128 + 4 pad)

typedef __bf16 bf16x8 __attribute__((ext_vector_type(8)));
typedef __bf16 bf16x4 __attribute__((ext_vector_type(4)));
typedef float  f32x4  __attribute__((ext_vector_type(4)));
typedef unsigned long ulongx2 __attribute__((ext_vector_type(2)));

// ---- weight pre-transform: wt[o][k]; k<128 -> bw[o][k]; else sw[o][k-128] ----
__global__ void build_wt(const float* __restrict__ bwl, const float* __restrict__ swl,
                         const float* __restrict__ bwc, const float* __restrict__ swc,
                         __bf16* __restrict__ wtl, __bf16* __restrict__ wtc) {
    int gid = blockIdx.x * 256 + threadIdx.x;      // 128*1152 threads in x
    const float* bw = blockIdx.y ? bwc : bwl;
    const float* sw = blockIdx.y ? swc : swl;
    __bf16*      wt = blockIdx.y ? wtc : wtl;
    int o = gid / KW;
    int k = gid - o * KW;
    float v = (k < 128) ? bw[o * DF + k] : sw[o * 1024 + (k - 128)];
    wt[gid] = (__bf16)v;
}

// ---- bf16 shadow of x ----
__global__ void cast_x(const float* __restrict__ x, __bf16* __restrict__ xb) {
    int i = blockIdx.x * 256 + threadIdx.x;
    f32x4 a = ((const f32x4*)x)[2 * i];
    f32x4 b = ((const f32x4*)x)[2 * i + 1];
    bf16x8 o;
    o[0] = (__bf16)a[0]; o[1] = (__bf16)a[1]; o[2] = (__bf16)a[2]; o[3] = (__bf16)a[3];
    o[4] = (__bf16)b[0]; o[5] = (__bf16)b[1]; o[6] = (__bf16)b[2]; o[7] = (__bf16)b[3];
    ((bf16x8*)xb)[i] = o;
}

// ---------------- CSR build ----------------
__global__ void deg_count(const int* __restrict__ ei, int* __restrict__ deg) {
    int e = blockIdx.x * 256 + threadIdx.x;
    if (e >= NEDGES) return;
    atomicAdd(&deg[ei[NEDGES + e]], 1);
}

#define SCHUNK 49
__global__ __launch_bounds__(1024) void scan_rowptr(const int* __restrict__ deg,
                                                    int* __restrict__ rowptr) {
    __shared__ int sums[1024];
    const int t = threadIdx.x;
    const int base = t * SCHUNK;
    int loc[SCHUNK];
    int s = 0;
#pragma unroll
    for (int j = 0; j < SCHUNK; ++j) {
        int i = base + j;
        int v = (i < NNODES) ? deg[i] : 0;
        loc[j] = s;
        s += v;
    }
    sums[t] = s;
    __syncthreads();
    for (int off = 1; off < 1024; off <<= 1) {
        int v = (t >= off) ? sums[t - off] : 0;
        __syncthreads();
        sums[t] += v;
        __syncthreads();
    }
    int excl = sums[t] - s;
#pragma unroll
    for (int j = 0; j < SCHUNK; ++j) {
        int i = base + j;
        if (i < NNODES) rowptr[i] = excl + loc[j];
    }
    if (t == 1023) rowptr[NNODES] = sums[1023];
}

__global__ void fill_csr(const int* __restrict__ ei, const int* __restrict__ deg,
                         const int* __restrict__ rowptr, int* __restrict__ cnt,
                         int* __restrict__ esrc, float* __restrict__ ew) {
    int e = blockIdx.x * 256 + threadIdx.x;
    if (e >= NEDGES) return;
    int s = ei[e];
    int d = ei[NEDGES + e];
    float w = rsqrtf((float)(deg[s] + 1)) * rsqrtf((float)(deg[d] + 1));
    int p = rowptr[d] + atomicAdd(&cnt[d], 1);
    esrc[p] = s;
    ew[p] = w;
}

// ---- aggregation: 32-lane half-wave per node, bf16 in AND out ----
__global__ __launch_bounds__(256) void agg_gather(
        const int* __restrict__ rowptr, const int* __restrict__ esrc,
        const float* __restrict__ ew, const __bf16* __restrict__ hb,
        __bf16* __restrict__ aggb) {
    const int tid = blockIdx.x * 256 + threadIdx.x;
    const int n = tid >> 5;
    const int l = tid & 31;
    if (n >= NNODES) return;
    int p  = rowptr[n];
    const int pe = rowptr[n + 1];
    f32x4 acc = {0.0f, 0.0f, 0.0f, 0.0f};
    for (; p + 3 < pe; p += 4) {
        int   s0 = esrc[p],  s1 = esrc[p + 1], s2 = esrc[p + 2], s3 = esrc[p + 3];
        float w0 = ew[p],    w1 = ew[p + 1],   w2 = ew[p + 2],   w3 = ew[p + 3];
        bf16x4 v0 = *(const bf16x4*)(hb + (size_t)s0 * DF + l * 4);
        bf16x4 v1 = *(const bf16x4*)(hb + (size_t)s1 * DF + l * 4);
        bf16x4 v2 = *(const bf16x4*)(hb + (size_t)s2 * DF + l * 4);
        bf16x4 v3 = *(const bf16x4*)(hb + (size_t)s3 * DF + l * 4);
#pragma unroll
        for (int j = 0; j < 4; ++j)
            acc[j] += w0 * (float)v0[j] + w1 * (float)v1[j]
                    + w2 * (float)v2[j] + w3 * (float)v3[j];
    }
    for (; p < pe; ++p) {
        int   s0 = esrc[p];
        float w0 = ew[p];
        bf16x4 v0 = *(const bf16x4*)(hb + (size_t)s0 * DF + l * 4);
#pragma unroll
        for (int j = 0; j < 4; ++j) acc[j] += w0 * (float)v0[j];
    }
    bf16x4 o;
#pragma unroll
    for (int j = 0; j < 4; ++j) o[j] = (__bf16)acc[j];
    *(bf16x4*)(aggb + (size_t)n * DF + l * 4) = o;
}

// ---- fused Euler step: out = h + EPS*(kanl(h) + kanc(agg)) -------------------
// Concatenated K = 72 chunks of 32. t<36: branch L (xb, wtl); else C (aggb, wtc).
// Per branch: ck<4 silu (i = ck*32+kk); else spline k = 128+i*8+b, i=(ck-4)*4+q, b=j.
// Tile 64 rows x 128 cols; waves 2x2: wave (wr,wc) = rows [wr*32,+32) x cols [wc*64,+64).
// A fragments built IN-REGISTER (funnel-shift basis pack); x from per-branch LDS tile.
// B LDS double-buffered w/ register prefetch, 1 barrier/chunk.
__global__ __launch_bounds__(256) void kan_step(
        const float* __restrict__ h,          // f32 state (epilogue read)
        const __bf16* __restrict__ xb,        // bf16 shadow of h (branch L)
        const __bf16* __restrict__ aggb,      // bf16 aggregate (branch C)
        const __bf16* __restrict__ wtl, const __bf16* __restrict__ wtc,
        float* __restrict__ out, __bf16* __restrict__ outb) {
    __shared__ __bf16 Bs[2][128 * 40];       // [buf][o][kk], stride 40
    __shared__ __bf16 Xs[64 * XSS];          // x-tile for current branch

    const int tid  = threadIdx.x;
    const int lane = tid & 63;
    const int w    = tid >> 6;
    const int wr   = w >> 1, wc = w & 1;
    const int q    = lane >> 4, l15 = lane & 15;
    const int n0   = blockIdx.x * 64;

    const int so = tid & 127, sh = tid >> 7;         // B staging
    const int bbase = so * 40 + sh * 16;
    const size_t wrow = (size_t)so * KW + sh * 16;

    const int xrow = tid >> 2, xseg = tid & 3;       // X staging: 64B per thread
    const bool xok = (n0 + xrow) < NNODES;
    const size_t xgoff = (size_t)(n0 + xrow) * DF + xseg * 32;
    const int xloff = xrow * XSS + xseg * 32;

    const int lr0 = wr * 32 + l15;                   // expansion rows (mi=0; mi=1 = +16)

    f32x4 acc[2][4] = {};
    uint4 g0, g1;                                    // B prefetch regs

    auto stage_x = [&](const __bf16* src) {
        uint4 v0 = {}, v1 = {}, v2 = {}, v3 = {};
        if (xok) {
            const uint4* g = (const uint4*)(src + xgoff);
            v0 = g[0]; v1 = g[1]; v2 = g[2]; v3 = g[3];
        }
        *(uint4*)&Xs[xloff]      = v0;
        *(uint4*)&Xs[xloff + 8]  = v1;
        *(uint4*)&Xs[xloff + 16] = v2;
        *(uint4*)&Xs[xloff + 24] = v3;
    };

    auto loadB = [&](int tn) {
        const __bf16* wtp = (tn >= 36) ? wtc : wtl;
        const int ck = (tn >= 36) ? tn - 36 : tn;
        const uint4* gp = (const uint4*)(wtp + wrow + ck * 32);
        g0 = gp[0]; g1 = gp[1];
    };
    auto writeB = [&](int buf) {
        *(uint4*)&Bs[buf][bbase]     = g0;
        *(uint4*)&Bs[buf][bbase + 8] = g1;
    };

    auto spline_pack = [&](float x) -> bf16x8 {
        float f  = __builtin_fmaf(x, 2.5f, 5.5f);    // (x+2.2)/0.4
        float fi = floorf(f);
        int  idx = (int)fi;
        float u  = f - fi;
        float u2 = u * u, u3 = u2 * u;
        float om = 1.0f - u;
        float Wa = u3 * (1.0f / 6.0f);
        float Wb = (((-3.0f * u + 3.0f) * u + 3.0f) * u + 1.0f) * (1.0f / 6.0f);
        float Wc = ((3.0f * u - 6.0f) * u2 + 4.0f) * (1.0f / 6.0f);
        float Wd = om * om * om * (1.0f / 6.0f);
        unsigned long p =
              (unsigned long)__builtin_bit_cast(unsigned short, (__bf16)Wd)
            | ((unsigned long)__builtin_bit_cast(unsigned short, (__bf16)Wc) << 16)
            | ((unsigned long)__builtin_bit_cast(unsigned short, (__bf16)Wb) << 32)
            | ((unsigned long)__builtin_bit_cast(unsigned short, (__bf16)Wa) << 48);
        int tt = idx - 3;                            // slot of Wd in [0,8)
        unsigned long lo, hi;
        if (tt >= 0) {
            int s = (tt & 3) * 16;
            unsigned long sv = p << s;
            unsigned long cr = (p >> (63 - s)) >> 1; // == p>>(64-s), s==0 safe
            bool hh = tt >= 4;
            lo = hh ? 0ul : sv;
            hi = hh ? sv : cr;
            if (tt >= 8) { lo = 0; hi = 0; }
        } else {
            int s = (-tt) * 16;
            lo = (tt >= -3) ? (p >> (s & 63)) : 0ul;
            hi = 0;
        }
        ulongx2 r; r[0] = lo; r[1] = hi;
        return __builtin_bit_cast(bf16x8, r);
    };

    auto silu8 = [&](const __bf16* xs) -> bf16x8 {
        bf16x8 v = *(const bf16x8*)xs;
        bf16x8 o;
#pragma unroll
        for (int j = 0; j < 8; ++j) {
            float x = (float)v[j];
            o[j] = (__bf16)(x / (1.0f + __expf(-x)));
        }
        return o;
    };

    stage_x(xb);
    loadB(0); writeB(0);
    __syncthreads();

#pragma unroll 2
    for (int t = 0; t < 72; ++t) {
        const int buf = t & 1;
        const bool more = t + 1 < 72;
        if (more) loadB(t + 1);                      // global B prefetch in flight

        const int ck = (t >= 36) ? t - 36 : t;
        bf16x8 a0, a1;
        if (ck < 4) {
            const int io = ck * 32 + q * 8;
            a0 = silu8(&Xs[lr0 * XSS + io]);
            a1 = silu8(&Xs[(lr0 + 16) * XSS + io]);
        } else {
            const int ii = (ck - 4) * 4 + q;
            unsigned short u0 = *(const unsigned short*)&Xs[lr0 * XSS + ii];
            unsigned short u1 = *(const unsigned short*)&Xs[(lr0 + 16) * XSS + ii];
            float x0 = __builtin_bit_cast(float, (unsigned)u0 << 16);
            float x1 = __builtin_bit_cast(float, (unsigned)u1 << 16);
            a0 = spline_pack(x0);
            a1 = spline_pack(x1);
        }

        bf16x8 bF[4];
#pragma unroll
        for (int nj = 0; nj < 4; ++nj)
            bF[nj] = *(const bf16x8*)&Bs[buf][(wc * 64 + nj * 16 + l15) * 40 + q * 8];
#pragma unroll
        for (int nj = 0; nj < 4; ++nj) {
            acc[0][nj] = __builtin_amdgcn_mfma_f32_16x16x32_bf16(a0, bF[nj], acc[0][nj], 0, 0, 0);
            acc[1][nj] = __builtin_amdgcn_mfma_f32_16x16x32_bf16(a1, bF[nj], acc[1][nj], 0, 0, 0);
        }

        if (t == 35) {                               // branch switch: restage x-tile
            __syncthreads();                         // all branch-L Xs reads done
            stage_x(aggb);
        }
        if (more) writeB(buf ^ 1);
        __syncthreads();
    }

    // epilogue: Euler; D layout row = q*4+r, col = l15 (m89-verified)
#pragma unroll
    for (int mi = 0; mi < 2; ++mi) {
#pragma unroll
        for (int nj = 0; nj < 4; ++nj) {
#pragma unroll
            for (int r = 0; r < 4; ++r) {
                int row = n0 + wr * 32 + mi * 16 + q * 4 + r;
                int col = wc * 64 + nj * 16 + l15;
                if (row < NNODES) {
                    size_t idx = (size_t)row * DF + col;
                    float v = h[idx] + EPS * acc[mi][nj][r];
                    out[idx]  = v;
                    outb[idx] = (__bf16)v;
                }
            }
        }
    }
}

extern "C" void kernel_launch(void* const* d_in, const int* in_sizes, int n_in,
                              void* d_out, int out_size, void* d_ws, size_t ws_size,
                              hipStream_t stream) {
    const float* x   = (const float*)d_in[0];
    const int*   ei  = (const int*)d_in[1];     // edge_index [2,E] int32
    const float* bwl = (const float*)d_in[2];
    const float* swl = (const float*)d_in[3];
    const float* bwc = (const float*)d_in[4];
    const float* swc = (const float*)d_in[5];
    float* out = (float*)d_out;

    char* ws = (char*)d_ws;
    int*    deg    = (int*)  (ws + 0);            //   200,000
    int*    cnt    = (int*)  (ws + 200000);       //   200,000 (adjacent: single memset)
    int*    rowptr = (int*)  (ws + 400000);       //   200,004
    int*    esrc   = (int*)  (ws + 600064);       // 3,200,000
    float*  ew     = (float*)(ws + 3800064);      // 3,200,000
    __bf16* xb     = (__bf16*)(ws + 7000064);     // 12,800,000
    __bf16* aggb   = (__bf16*)(ws + 19800064);    // 12,800,000
    __bf16* wtl    = (__bf16*)(ws + 32600064);    //    294,912
    __bf16* wtc    = (__bf16*)(ws + 32894976);    //    294,912  (total ~33.2 MB)

    build_wt<<<dim3((DF * KW) / 256, 2), 256, 0, stream>>>(bwl, swl, bwc, swc, wtl, wtc);
    cast_x<<<3125, 256, 0, stream>>>(x, xb);

    hipMemsetAsync(deg, 0, 400000, stream);       // deg + cnt
    deg_count<<<3125, 256, 0, stream>>>(ei, deg);
    scan_rowptr<<<1, 1024, 0, stream>>>(deg, rowptr);
    fill_csr<<<3125, 256, 0, stream>>>(ei, deg, rowptr, cnt, esrc, ew);

    const int gemm_grid = (NNODES + 63) / 64;     // 782
    const float* h = x;
    for (int step = 0; step < 2; ++step) {        // delta_t = 2
        agg_gather<<<6250, 256, 0, stream>>>(rowptr, esrc, ew, xb, aggb);
        kan_step<<<gemm_grid, 256, 0, stream>>>(h, xb, aggb, wtl, wtc, out, xb);
        h = out;
    }
}

// Round 8
// 401.177 us; speedup vs baseline: 1.1885x; 1.1885x over previous
//
#include <hip/hip_runtime.h>
#include <hip/hip_bf16.h>

#define NNODES 50000
#define NEDGES 800000
#define DF 128
#define KW 1152                // K per branch: 128 silu + 1024 spline (native order)
#define EPS 0.001f
#define XSS 132                // Xs row stride in bf16 elems (128 + 4 pad)
#define NB 196                 // scan blocks: 196*256 >= 50000

typedef __bf16 bf16x8 __attribute__((ext_vector_type(8)));
typedef __bf16 bf16x4 __attribute__((ext_vector_type(4)));
typedef float  f32x4  __attribute__((ext_vector_type(4)));
typedef unsigned long ulongx2 __attribute__((ext_vector_type(2)));

// ---- weight pre-transform: wt[o][k]; k<128 -> bw[o][k]; else sw[o][k-128] ----
__global__ void build_wt(const float* __restrict__ bwl, const float* __restrict__ swl,
                         const float* __restrict__ bwc, const float* __restrict__ swc,
                         __bf16* __restrict__ wtl, __bf16* __restrict__ wtc) {
    int gid = blockIdx.x * 256 + threadIdx.x;      // 128*1152 threads in x
    const float* bw = blockIdx.y ? bwc : bwl;
    const float* sw = blockIdx.y ? swc : swl;
    __bf16*      wt = blockIdx.y ? wtc : wtl;
    int o = gid / KW;
    int k = gid - o * KW;
    float v = (k < 128) ? bw[o * DF + k] : sw[o * 1024 + (k - 128)];
    wt[gid] = (__bf16)v;
}

// ---- bf16 shadow of x ----
__global__ void cast_x(const float* __restrict__ x, __bf16* __restrict__ xb) {
    int i = blockIdx.x * 256 + threadIdx.x;
    f32x4 a = ((const f32x4*)x)[2 * i];
    f32x4 b = ((const f32x4*)x)[2 * i + 1];
    bf16x8 o;
    o[0] = (__bf16)a[0]; o[1] = (__bf16)a[1]; o[2] = (__bf16)a[2]; o[3] = (__bf16)a[3];
    o[4] = (__bf16)b[0]; o[5] = (__bf16)b[1]; o[6] = (__bf16)b[2]; o[7] = (__bf16)b[3];
    ((bf16x8*)xb)[i] = o;
}

// ---------------- CSR build ----------------
__global__ void deg_count(const int* __restrict__ ei, int* __restrict__ deg) {
    int e = blockIdx.x * 256 + threadIdx.x;
    if (e >= NEDGES) return;
    atomicAdd(&deg[ei[NEDGES + e]], 1);
}

// 3-kernel multi-block exclusive scan of deg -> rowptr
__global__ void scan_part(const int* __restrict__ deg, int* __restrict__ bsum) {
    __shared__ int red[256];
    int t = threadIdx.x;
    int i = blockIdx.x * 256 + t;
    red[t] = (i < NNODES) ? deg[i] : 0;
    __syncthreads();
    for (int off = 128; off > 0; off >>= 1) {
        if (t < off) red[t] += red[t + off];
        __syncthreads();
    }
    if (t == 0) bsum[blockIdx.x] = red[0];
}

__global__ void scan_bsum(const int* __restrict__ bsum, int* __restrict__ boff) {
    __shared__ int buf[256];
    int t = threadIdx.x;
    int v = (t < NB) ? bsum[t] : 0;
    buf[t] = v;
    __syncthreads();
    for (int off = 1; off < 256; off <<= 1) {
        int x = (t >= off) ? buf[t - off] : 0;
        __syncthreads();
        buf[t] += x;
        __syncthreads();
    }
    if (t <= NB) boff[t] = buf[t] - ((t < NB) ? bsum[t] : 0);   // exclusive; boff[NB]=total
}

__global__ void scan_final(const int* __restrict__ deg, const int* __restrict__ boff,
                           int* __restrict__ rowptr) {
    __shared__ int buf[256];
    int t = threadIdx.x;
    int i = blockIdx.x * 256 + t;
    int v = (i < NNODES) ? deg[i] : 0;
    buf[t] = v;
    __syncthreads();
    for (int off = 1; off < 256; off <<= 1) {
        int x = (t >= off) ? buf[t - off] : 0;
        __syncthreads();
        buf[t] += x;
        __syncthreads();
    }
    if (i < NNODES) rowptr[i] = buf[t] - v + boff[blockIdx.x];
    if (blockIdx.x == 0 && t == 0) rowptr[NNODES] = boff[NB];
}

__global__ void fill_csr(const int* __restrict__ ei, const int* __restrict__ deg,
                         const int* __restrict__ rowptr, int* __restrict__ cnt,
                         int* __restrict__ esrc, float* __restrict__ ew) {
    int e = blockIdx.x * 256 + threadIdx.x;
    if (e >= NEDGES) return;
    int s = ei[e];
    int d = ei[NEDGES + e];
    float w = rsqrtf((float)(deg[s] + 1)) * rsqrtf((float)(deg[d] + 1));
    int p = rowptr[d] + atomicAdd(&cnt[d], 1);
    esrc[p] = s;
    ew[p] = w;
}

// ---- aggregation: 32-lane half-wave per node, bf16 in/out, index pipelining ----
__global__ __launch_bounds__(256) void agg_gather(
        const int* __restrict__ rowptr, const int* __restrict__ esrc,
        const float* __restrict__ ew, const __bf16* __restrict__ hb,
        __bf16* __restrict__ aggb) {
    const int tid = blockIdx.x * 256 + threadIdx.x;
    const int n = tid >> 5;
    const int l = tid & 31;
    if (n >= NNODES) return;
    int p  = rowptr[n];
    const int pe = rowptr[n + 1];
    f32x4 acc = {0.0f, 0.0f, 0.0f, 0.0f};
    int   cs0, cs1, cs2, cs3;
    float cw0, cw1, cw2, cw3;
    bool have = (p + 3 < pe);
    if (have) {
        cs0 = esrc[p]; cs1 = esrc[p + 1]; cs2 = esrc[p + 2]; cs3 = esrc[p + 3];
        cw0 = ew[p];   cw1 = ew[p + 1];   cw2 = ew[p + 2];   cw3 = ew[p + 3];
    }
    while (have) {
        int np = p + 4;
        bool nh = (np + 3 < pe);
        int   ns0 = 0, ns1 = 0, ns2 = 0, ns3 = 0;
        float nw0 = 0, nw1 = 0, nw2 = 0, nw3 = 0;
        if (nh) {
            ns0 = esrc[np]; ns1 = esrc[np + 1]; ns2 = esrc[np + 2]; ns3 = esrc[np + 3];
            nw0 = ew[np];   nw1 = ew[np + 1];   nw2 = ew[np + 2];   nw3 = ew[np + 3];
        }
        bf16x4 v0 = *(const bf16x4*)(hb + (size_t)cs0 * DF + l * 4);
        bf16x4 v1 = *(const bf16x4*)(hb + (size_t)cs1 * DF + l * 4);
        bf16x4 v2 = *(const bf16x4*)(hb + (size_t)cs2 * DF + l * 4);
        bf16x4 v3 = *(const bf16x4*)(hb + (size_t)cs3 * DF + l * 4);
#pragma unroll
        for (int j = 0; j < 4; ++j)
            acc[j] += cw0 * (float)v0[j] + cw1 * (float)v1[j]
                    + cw2 * (float)v2[j] + cw3 * (float)v3[j];
        p = np;
        cs0 = ns0; cs1 = ns1; cs2 = ns2; cs3 = ns3;
        cw0 = nw0; cw1 = nw1; cw2 = nw2; cw3 = nw3;
        have = nh;
    }
    for (; p < pe; ++p) {
        int   s0 = esrc[p];
        float w0 = ew[p];
        bf16x4 v0 = *(const bf16x4*)(hb + (size_t)s0 * DF + l * 4);
#pragma unroll
        for (int j = 0; j < 4; ++j) acc[j] += w0 * (float)v0[j];
    }
    bf16x4 o;
#pragma unroll
    for (int j = 0; j < 4; ++j) o[j] = (__bf16)acc[j];
    *(bf16x4*)(aggb + (size_t)n * DF + l * 4) = o;
}

// ---- fused Euler step: out = h + EPS*(kanl(h) + kanc(agg)) -------------------
// Concatenated K = 72 chunks of 32. t<36: branch L (xb, wtl); else C (aggb, wtc).
// Per branch: ck<4 silu (i = ck*32+kk); else spline k = 128+i*8+b, i=(ck-4)*4+q, b=j.
// ROW-SPLIT waves: wave w = rows [w*16, w*16+16) x ALL 128 cols -> expansion computed
// exactly once per x-element (no duplication). A built in-register (funnel-shift pack);
// x from per-branch LDS tile. B LDS double-buffered w/ register prefetch, 1 barrier/chunk.
__global__ __launch_bounds__(256, 4) void kan_step(
        const float* __restrict__ h,          // f32 state (epilogue read)
        const __bf16* __restrict__ xb,        // bf16 shadow of h (branch L)
        const __bf16* __restrict__ aggb,      // bf16 aggregate (branch C)
        const __bf16* __restrict__ wtl, const __bf16* __restrict__ wtc,
        float* __restrict__ out, __bf16* __restrict__ outb) {
    __shared__ __bf16 Bs[2][128 * 40];       // [buf][o][kk], stride 40 (80B rows, 16B-aligned)
    __shared__ __bf16 Xs[64 * XSS];          // x-tile for current branch

    const int tid  = threadIdx.x;
    const int lane = tid & 63;
    const int w    = tid >> 6;               // wave -> rows [w*16, +16)
    const int q    = lane >> 4, l15 = lane & 15;
    const int n0   = blockIdx.x * 64;

    const int so = tid & 127, sh = tid >> 7;         // B staging
    const int bbase = so * 40 + sh * 16;
    const size_t wrow = (size_t)so * KW + sh * 16;

    const int xrow = tid >> 2, xseg = tid & 3;       // X staging: 64B per thread
    const bool xok = (n0 + xrow) < NNODES;
    const size_t xgoff = (size_t)(n0 + xrow) * DF + xseg * 32;
    const int xloff = xrow * XSS + xseg * 32;

    const int myrow = w * 16 + l15;                  // this lane's expansion row

    f32x4 acc[8] = {};
    uint4 g0, g1;                                    // B prefetch regs

    auto stage_x = [&](const __bf16* src) {
        uint4 v0 = {}, v1 = {}, v2 = {}, v3 = {};
        if (xok) {
            const uint4* g = (const uint4*)(src + xgoff);
            v0 = g[0]; v1 = g[1]; v2 = g[2]; v3 = g[3];
        }
        *(uint4*)&Xs[xloff]      = v0;
        *(uint4*)&Xs[xloff + 8]  = v1;
        *(uint4*)&Xs[xloff + 16] = v2;
        *(uint4*)&Xs[xloff + 24] = v3;
    };

    auto loadB = [&](int tn) {
        const __bf16* wtp = (tn >= 36) ? wtc : wtl;
        const int ck = (tn >= 36) ? tn - 36 : tn;
        const uint4* gp = (const uint4*)(wtp + wrow + ck * 32);
        g0 = gp[0]; g1 = gp[1];
    };
    auto writeB = [&](int buf) {
        *(uint4*)&Bs[buf][bbase]     = g0;
        *(uint4*)&Bs[buf][bbase + 8] = g1;
    };

    auto spline_pack = [&](float x) -> bf16x8 {
        float f  = __builtin_fmaf(x, 2.5f, 5.5f);    // (x+2.2)/0.4
        float fi = floorf(f);
        int  idx = (int)fi;
        float u  = f - fi;
        float u2 = u * u, u3 = u2 * u;
        float om = 1.0f - u;
        float Wa = u3 * (1.0f / 6.0f);
        float Wb = (((-3.0f * u + 3.0f) * u + 3.0f) * u + 1.0f) * (1.0f / 6.0f);
        float Wc = ((3.0f * u - 6.0f) * u2 + 4.0f) * (1.0f / 6.0f);
        float Wd = om * om * om * (1.0f / 6.0f);
        unsigned long p =
              (unsigned long)__builtin_bit_cast(unsigned short, (__bf16)Wd)
            | ((unsigned long)__builtin_bit_cast(unsigned short, (__bf16)Wc) << 16)
            | ((unsigned long)__builtin_bit_cast(unsigned short, (__bf16)Wb) << 32)
            | ((unsigned long)__builtin_bit_cast(unsigned short, (__bf16)Wa) << 48);
        int tt = idx - 3;                            // slot of Wd in [0,8)
        unsigned long lo, hi;
        if (tt >= 0) {
            int s = (tt & 3) * 16;
            unsigned long sv = p << s;
            unsigned long cr = (p >> (63 - s)) >> 1; // == p>>(64-s), s==0 safe
            bool hh = tt >= 4;
            lo = hh ? 0ul : sv;
            hi = hh ? sv : cr;
            if (tt >= 8) { lo = 0; hi = 0; }
        } else {
            int s = (-tt) * 16;
            lo = (tt >= -3) ? (p >> (s & 63)) : 0ul;
            hi = 0;
        }
        ulongx2 r; r[0] = lo; r[1] = hi;
        return __builtin_bit_cast(bf16x8, r);
    };

    auto silu8 = [&](const __bf16* xs) -> bf16x8 {
        bf16x8 v = *(const bf16x8*)xs;
        bf16x8 o;
#pragma unroll
        for (int j = 0; j < 8; ++j) {
            float x = (float)v[j];
            o[j] = (__bf16)(x / (1.0f + __expf(-x)));
        }
        return o;
    };

    stage_x(xb);
    loadB(0); writeB(0);
    __syncthreads();

#pragma unroll 2
    for (int t = 0; t < 72; ++t) {
        const int buf = t & 1;
        const bool more = t + 1 < 72;
        if (more) loadB(t + 1);                      // global B prefetch in flight

        const int ck = (t >= 36) ? t - 36 : t;
        bf16x8 a;
        if (ck < 4) {
            a = silu8(&Xs[myrow * XSS + ck * 32 + q * 8]);
        } else {
            unsigned short u0 = *(const unsigned short*)&Xs[myrow * XSS + (ck - 4) * 4 + q];
            a = spline_pack(__builtin_bit_cast(float, (unsigned)u0 << 16));
        }

        bf16x8 bF[8];
#pragma unroll
        for (int nj = 0; nj < 8; ++nj)
            bF[nj] = *(const bf16x8*)&Bs[buf][(nj * 16 + l15) * 40 + q * 8];
#pragma unroll
        for (int nj = 0; nj < 8; ++nj)
            acc[nj] = __builtin_amdgcn_mfma_f32_16x16x32_bf16(a, bF[nj], acc[nj], 0, 0, 0);

        if (t == 35) {                               // branch switch: restage x-tile
            __syncthreads();                         // all branch-L Xs reads done
            stage_x(aggb);
        }
        if (more) writeB(buf ^ 1);
        __syncthreads();
    }

    // epilogue: Euler; D layout row = q*4+r, col = l15 (m89-verified)
#pragma unroll
    for (int nj = 0; nj < 8; ++nj) {
#pragma unroll
        for (int r = 0; r < 4; ++r) {
            int row = n0 + w * 16 + q * 4 + r;
            int col = nj * 16 + l15;
            if (row < NNODES) {
                size_t idx = (size_t)row * DF + col;
                float v = h[idx] + EPS * acc[nj][r];
                out[idx]  = v;
                outb[idx] = (__bf16)v;
            }
        }
    }
}

extern "C" void kernel_launch(void* const* d_in, const int* in_sizes, int n_in,
                              void* d_out, int out_size, void* d_ws, size_t ws_size,
                              hipStream_t stream) {
    const float* x   = (const float*)d_in[0];
    const int*   ei  = (const int*)d_in[1];     // edge_index [2,E] int32
    const float* bwl = (const float*)d_in[2];
    const float* swl = (const float*)d_in[3];
    const float* bwc = (const float*)d_in[4];
    const float* swc = (const float*)d_in[5];
    float* out = (float*)d_out;

    char* ws = (char*)d_ws;
    int*    deg    = (int*)  (ws + 0);            //   200,000
    int*    cnt    = (int*)  (ws + 200000);       //   200,000 (adjacent: single memset)
    int*    rowptr = (int*)  (ws + 400000);       //   200,004
    int*    bsum   = (int*)  (ws + 600064);       //       784
    int*    boff   = (int*)  (ws + 600896);       //       788
    int*    esrc   = (int*)  (ws + 601728);       // 3,200,000
    float*  ew     = (float*)(ws + 3801728);      // 3,200,000
    __bf16* xb     = (__bf16*)(ws + 7001728);     // 12,800,000
    __bf16* aggb   = (__bf16*)(ws + 19801728);    // 12,800,000
    __bf16* wtl    = (__bf16*)(ws + 32601728);    //    294,912
    __bf16* wtc    = (__bf16*)(ws + 32896640);    //    294,912  (total ~33.2 MB)

    build_wt<<<dim3((DF * KW) / 256, 2), 256, 0, stream>>>(bwl, swl, bwc, swc, wtl, wtc);
    cast_x<<<3125, 256, 0, stream>>>(x, xb);

    hipMemsetAsync(deg, 0, 400000, stream);       // deg + cnt
    deg_count<<<3125, 256, 0, stream>>>(ei, deg);
    scan_part<<<NB, 256, 0, stream>>>(deg, bsum);
    scan_bsum<<<1, 256, 0, stream>>>(bsum, boff);
    scan_final<<<NB, 256, 0, stream>>>(deg, boff, rowptr);
    fill_csr<<<3125, 256, 0, stream>>>(ei, deg, rowptr, cnt, esrc, ew);

    const int gemm_grid = (NNODES + 63) / 64;     // 782
    const float* h = x;
    for (int step = 0; step < 2; ++step) {        // delta_t = 2
        agg_gather<<<6250, 256, 0, stream>>>(rowptr, esrc, ew, xb, aggb);
        kan_step<<<gemm_grid, 256, 0, stream>>>(h, xb, aggb, wtl, wtc, out, xb);
        h = out;
    }
}